// Round 1
// baseline (1666.955 us; speedup 1.0000x reference)
//
#include <hip/hip_runtime.h>

#define NN   100000
#define EE   1600000
#define FDIM 128
#define NFAC 4
#define DD   64
#define NLAY 3
#define GG   128

// prep weight buffer layout (bf16 elems), per-factor stride:
#define PF_STRIDE 57344
#define OFF_WREL  8192
#define OFF_WROOT 20480
#define OFF_WIH   32768
#define OFF_WHH   45056
#define PREP_TOTAL (NFAC * PF_STRIDE)   // 229376

typedef __bf16 bf16x8_t __attribute__((ext_vector_type(8)));
typedef float  f32x4_t  __attribute__((ext_vector_type(4)));

__device__ __forceinline__ unsigned short f2bf(float x) {
    unsigned u = __float_as_uint(x);
    u += 0x7fffu + ((u >> 16) & 1u);        // round-to-nearest-even
    return (unsigned short)(u >> 16);
}
__device__ __forceinline__ float b2f(unsigned short h) {
    return __uint_as_float(((unsigned)h) << 16);
}
__device__ __forceinline__ float sigm(float x) { return 1.f / (1.f + __expf(-x)); }
__device__ __forceinline__ float tanh_f(float x) {
    float t = __expf(-2.f * fabsf(x));
    float r = (1.f - t) / (1.f + t);
    return x >= 0.f ? r : -r;
}

// ---------------------------------------------------------------- init
__global__ __launch_bounds__(256) void k_init(int* deg, int* cursor, float* counts, float* outs) {
    int i = blockIdx.x * 256 + threadIdx.x;
    if (i < NN) { deg[i] = 0; cursor[i] = 0; }
    if (i < GG) counts[i] = 0.f;
    if (i < NFAC * GG * DD) outs[i] = 0.f;
}

// ------------------------------------------------- weight + x bf16 prep
// B-fragment order: for matrix B[k][n]: elem((nt*KB+kb)*64+lane)*8+j = B[kb*32+(lane>>4)*8+j][nt*16+(lane&15)]
__global__ __launch_bounds__(256) void k_prep(const float* x, const float* linW,
                                              const float* wrel, const float* wroot,
                                              const float* wih, const float* whh,
                                              unsigned short* x16, unsigned short* prep) {
    for (int i = blockIdx.x * 256 + threadIdx.x; i < NN * FDIM; i += gridDim.x * 256)
        x16[i] = f2bf(x[i]);
    for (int idx = blockIdx.x * 256 + threadIdx.x; idx < PREP_TOTAL; idx += gridDim.x * 256) {
        int f = idx / PF_STRIDE, r = idx % PF_STRIDE;
        int e, KB, mode, l = 0;
        if (r < OFF_WREL)       { e = r;                 KB = 4; mode = 0; }
        else if (r < OFF_WROOT) { int rr = r - OFF_WREL;  l = rr >> 12; e = rr & 4095; KB = 2; mode = 1; }
        else if (r < OFF_WIH)   { int rr = r - OFF_WROOT; l = rr >> 12; e = rr & 4095; KB = 2; mode = 2; }
        else if (r < OFF_WHH)   { e = r - OFF_WIH;        KB = 2; mode = 3; }
        else                    { e = r - OFF_WHH;        KB = 2; mode = 4; }
        int j = e & 7, lane = (e >> 3) & 63, t = e >> 9;
        int kb = t % KB, nt = t / KB;
        int k = kb * 32 + (lane >> 4) * 8 + j;
        int n = nt * 16 + (lane & 15);
        float v;
        if (mode == 0)      v = linW[(f * FDIM + k) * DD + n];
        else if (mode == 1) v = wrel[((f * 3 + l) * DD + k) * DD + n];
        else if (mode == 2) v = wroot[((f * 3 + l) * DD + k) * DD + n];
        else if (mode == 3) v = wih[(f * 192 + n) * DD + k];   // B = Wih^T
        else                v = whh[(f * 192 + n) * DD + k];
        prep[idx] = f2bf(v);
    }
}

// ---------------------------------------------------------------- counts / CSR build
__global__ __launch_bounds__(256) void k_count(const int* batch, float* counts) {
    int n = blockIdx.x * 256 + threadIdx.x;
    if (n < NN) atomicAdd(&counts[batch[n]], 1.f);
}
__global__ __launch_bounds__(256) void k_deg(const int* ei, int* deg) {
    int e = blockIdx.x * 256 + threadIdx.x;
    if (e < EE) atomicAdd(&deg[ei[EE + e]], 1);
}
__global__ __launch_bounds__(256) void k_scan1(const int* deg, int* row_pos, int* bsum) {
    __shared__ int lds[256];
    int tid = threadIdx.x, idx = blockIdx.x * 256 + tid;
    int v = (idx < NN) ? deg[idx] : 0;
    lds[tid] = v; __syncthreads();
    for (int s = 1; s < 256; s <<= 1) {
        int t = (tid >= s) ? lds[tid - s] : 0;
        __syncthreads();
        lds[tid] += t;
        __syncthreads();
    }
    if (idx < NN) row_pos[idx] = lds[tid] - v;   // exclusive within block
    if (tid == 255) bsum[blockIdx.x] = lds[255];
}
__global__ __launch_bounds__(512) void k_scan2(int* bsum) {  // 1 block, 512 threads, 391 valid
    __shared__ int lds[512];
    int tid = threadIdx.x;
    int v = (tid < 391) ? bsum[tid] : 0;
    lds[tid] = v; __syncthreads();
    for (int s = 1; s < 512; s <<= 1) {
        int t = (tid >= s) ? lds[tid - s] : 0;
        __syncthreads();
        lds[tid] += t;
        __syncthreads();
    }
    bsum[tid] = lds[tid] - v;                    // exclusive block offsets
}
__global__ __launch_bounds__(256) void k_fill(const int* ei, const float* att,
                                              const int* row_pos, const int* boff, int* cursor,
                                              int* csr_src, float4* csr_att4) {
    int e = blockIdx.x * 256 + threadIdx.x;
    if (e >= EE) return;
    int d = ei[EE + e];
    int slot = row_pos[d] + boff[d >> 8] + atomicAdd(&cursor[d], 1);
    csr_src[slot] = ei[e];
    csr_att4[slot] = make_float4(att[e], att[EE + e], att[2 * EE + e], att[3 * EE + e]);
}

// ---------------------------------------------------------------- lin: out16[f] = bf16(x @ linW[f] + b[f])
__global__ __launch_bounds__(256) void k_lin(const unsigned short* x16, const unsigned short* prep,
                                             const float* linb, unsigned short* out16) {
    int f = blockIdx.y, n0 = blockIdx.x * 64;
    __shared__ unsigned short xs[64 * 136];      // 128 cols + 8 pad
    int tid = threadIdx.x;
    for (int t = tid; t < 1024; t += 256) {      // 64 rows x 16 segs x 8 elems
        int row = t >> 4, seg = t & 15;
        int gn = n0 + row; if (gn >= NN) gn = NN - 1;
        *(uint4*)(xs + row * 136 + seg * 8) = *(const uint4*)(x16 + gn * FDIM + seg * 8);
    }
    __syncthreads();
    int w = tid >> 6, lane = tid & 63, mrow = lane & 15, q = lane >> 4;
    const unsigned short* wp = prep + f * PF_STRIDE;
#pragma unroll
    for (int nt = 0; nt < 4; nt++) {
        f32x4_t acc = {0.f, 0.f, 0.f, 0.f};
#pragma unroll
        for (int kb = 0; kb < 4; kb++) {
            bf16x8_t a = *(const bf16x8_t*)(xs + (w * 16 + mrow) * 136 + kb * 32 + q * 8);
            bf16x8_t b = *(const bf16x8_t*)(wp + ((nt * 4 + kb) * 64 + lane) * 8);
            acc = __builtin_amdgcn_mfma_f32_16x16x32_bf16(a, b, acc, 0, 0, 0);
        }
        int col = nt * 16 + mrow;
        float bias = linb[f * DD + col];
#pragma unroll
        for (int r = 0; r < 4; r++) {
            int node = n0 + w * 16 + q * 4 + r;
            if (node < NN) out16[((size_t)f * NN + node) * DD + col] = f2bf(acc[r] + bias);
        }
    }
}

// ---------------------------------------------------------------- gather: agg16[f][n] = sum_e att[f][e]*out16[f][src]
__global__ __launch_bounds__(256) void k_gather(const int* row_pos, const int* boff, const int* deg,
                                                const int* csr_src, const float4* csr_att4,
                                                const unsigned short* out16, unsigned short* agg16) {
    int wave = threadIdx.x >> 6, lane = threadIdx.x & 63;
    int n = blockIdx.x * 4 + wave;
    if (n >= NN) return;
    int row = row_pos[n] + boff[n >> 8];
    int dg = deg[n];
    float a0 = 0.f, a1 = 0.f, a2 = 0.f, a3 = 0.f;
    int s_nxt = 0; float4 at_nxt = make_float4(0.f, 0.f, 0.f, 0.f);
    if (dg > 0) { s_nxt = csr_src[row]; at_nxt = csr_att4[row]; }
    for (int i = 0; i < dg; i++) {
        int s = s_nxt; float4 at = at_nxt;
        if (i + 1 < dg) { s_nxt = csr_src[row + i + 1]; at_nxt = csr_att4[row + i + 1]; }
        int base = s * DD + lane;
        float v0 = b2f(out16[(size_t)0 * NN * DD + base]);
        float v1 = b2f(out16[(size_t)1 * NN * DD + base]);
        float v2 = b2f(out16[(size_t)2 * NN * DD + base]);
        float v3 = b2f(out16[(size_t)3 * NN * DD + base]);
        a0 += at.x * v0; a1 += at.y * v1; a2 += at.z * v2; a3 += at.w * v3;
    }
    agg16[((size_t)0 * NN + n) * DD + lane] = f2bf(a0);
    agg16[((size_t)1 * NN + n) * DD + lane] = f2bf(a1);
    agg16[((size_t)2 * NN + n) * DD + lane] = f2bf(a2);
    agg16[((size_t)3 * NN + n) * DD + lane] = f2bf(a3);
}

// ---------------------------------------------------------------- fused layer: m = relu(agg@Wrel + out@Wroot + brel); h' = GRU(m, h=out)
__global__ __launch_bounds__(256) void k_layer(int l, const unsigned short* agg16, unsigned short* out16,
                                               const unsigned short* prep, const float* brel,
                                               const float* bih, const float* bhh,
                                               float* feats, int last) {
    int f = blockIdx.y, n0 = blockIdx.x * 64;
    __shared__ unsigned short A1[64 * 72];   // agg tile (pad 64->72)
    __shared__ unsigned short A2[64 * 72];   // out (=h) tile
    __shared__ unsigned short Mt[64 * 72];   // m tile
    int tid = threadIdx.x;
    for (int t = tid; t < 512; t += 256) {   // 64 rows x 8 segs x 8 elems
        int row = t >> 3, seg = t & 7;
        int gn = n0 + row; if (gn >= NN) gn = NN - 1;
        *(uint4*)(A1 + row * 72 + seg * 8) = *(const uint4*)(agg16 + ((size_t)f * NN + gn) * DD + seg * 8);
        *(uint4*)(A2 + row * 72 + seg * 8) = *(const uint4*)(out16 + ((size_t)f * NN + gn) * DD + seg * 8);
    }
    __syncthreads();
    int w = tid >> 6, lane = tid & 63, mrow = lane & 15, q = lane >> 4;
    const unsigned short* wrel  = prep + f * PF_STRIDE + OFF_WREL  + l * 4096;
    const unsigned short* wroot = prep + f * PF_STRIDE + OFF_WROOT + l * 4096;

    // phase 1: m
#pragma unroll
    for (int nt = 0; nt < 4; nt++) {
        f32x4_t acc = {0.f, 0.f, 0.f, 0.f};
#pragma unroll
        for (int kb = 0; kb < 2; kb++) {
            bf16x8_t a1 = *(const bf16x8_t*)(A1 + (w * 16 + mrow) * 72 + kb * 32 + q * 8);
            bf16x8_t b1 = *(const bf16x8_t*)(wrel + ((nt * 2 + kb) * 64 + lane) * 8);
            acc = __builtin_amdgcn_mfma_f32_16x16x32_bf16(a1, b1, acc, 0, 0, 0);
            bf16x8_t a2 = *(const bf16x8_t*)(A2 + (w * 16 + mrow) * 72 + kb * 32 + q * 8);
            bf16x8_t b2 = *(const bf16x8_t*)(wroot + ((nt * 2 + kb) * 64 + lane) * 8);
            acc = __builtin_amdgcn_mfma_f32_16x16x32_bf16(a2, b2, acc, 0, 0, 0);
        }
        int col = nt * 16 + mrow;
        float bias = brel[(f * 3 + l) * DD + col];
#pragma unroll
        for (int r = 0; r < 4; r++) {
            float mv = acc[r] + bias;
            mv = mv > 0.f ? mv : 0.f;
            Mt[(w * 16 + q * 4 + r) * 72 + col] = f2bf(mv);
        }
    }
    __syncthreads();

    // phase 2: gi = m@Wih^T, gh = h@Whh^T  (192 cols = 12 n-tiles)
    const unsigned short* wih = prep + f * PF_STRIDE + OFF_WIH;
    const unsigned short* whh = prep + f * PF_STRIDE + OFF_WHH;
    float g1[12][4], g2[12][4];
#pragma unroll
    for (int nt = 0; nt < 12; nt++) {
        f32x4_t acc1 = {0.f, 0.f, 0.f, 0.f}, acc2 = {0.f, 0.f, 0.f, 0.f};
#pragma unroll
        for (int kb = 0; kb < 2; kb++) {
            bf16x8_t am = *(const bf16x8_t*)(Mt + (w * 16 + mrow) * 72 + kb * 32 + q * 8);
            bf16x8_t bi = *(const bf16x8_t*)(wih + ((nt * 2 + kb) * 64 + lane) * 8);
            acc1 = __builtin_amdgcn_mfma_f32_16x16x32_bf16(am, bi, acc1, 0, 0, 0);
            bf16x8_t ah = *(const bf16x8_t*)(A2 + (w * 16 + mrow) * 72 + kb * 32 + q * 8);
            bf16x8_t bh = *(const bf16x8_t*)(whh + ((nt * 2 + kb) * 64 + lane) * 8);
            acc2 = __builtin_amdgcn_mfma_f32_16x16x32_bf16(ah, bh, acc2, 0, 0, 0);
        }
#pragma unroll
        for (int r = 0; r < 4; r++) { g1[nt][r] = acc1[r]; g2[nt][r] = acc2[r]; }
    }

    // gates
#pragma unroll
    for (int nt = 0; nt < 4; nt++) {
        int col = nt * 16 + mrow;
        float bi_r = bih[f * 192 + col],        bh_r = bhh[f * 192 + col];
        float bi_z = bih[f * 192 + 64 + col],   bh_z = bhh[f * 192 + 64 + col];
        float bi_n = bih[f * 192 + 128 + col],  bh_n = bhh[f * 192 + 128 + col];
#pragma unroll
        for (int r = 0; r < 4; r++) {
            float ir = g1[nt][r] + bi_r,      hr = g2[nt][r] + bh_r;
            float iz = g1[nt + 4][r] + bi_z,  hz = g2[nt + 4][r] + bh_z;
            float in_ = g1[nt + 8][r] + bi_n, hn = g2[nt + 8][r] + bh_n;
            float rg = sigm(ir + hr);
            float z  = sigm(iz + hz);
            float nn = tanh_f(in_ + rg * hn);
            float h  = b2f(A2[(w * 16 + q * 4 + r) * 72 + col]);
            float hp = (1.f - z) * nn + z * h;
            int node = n0 + w * 16 + q * 4 + r;
            if (node < NN) {
                out16[((size_t)f * NN + node) * DD + col] = f2bf(hp);
                if (last) feats[((size_t)f * NN + node) * DD + col] = hp;
            }
        }
    }
}

// ---------------------------------------------------------------- pool (batch is sorted -> segmented reduce, few atomics)
__global__ __launch_bounds__(256) void k_pool(const float* feats, const int* batch, float* outs) {
    int f = blockIdx.y, w = threadIdx.x >> 6, lane = threadIdx.x & 63;
    int nbase = blockIdx.x * 256 + w * 64;
    if (nbase >= NN) return;
    int g_cur = batch[nbase];
    float acc = 0.f;
    for (int i = 0; i < 64; i++) {
        int n = nbase + i;
        if (n >= NN) break;
        int g = batch[n];
        float v = feats[((size_t)f * NN + n) * DD + lane];
        if (g != g_cur) {
            atomicAdd(&outs[(f * GG + g_cur) * DD + lane], acc);
            acc = v; g_cur = g;
        } else acc += v;
    }
    atomicAdd(&outs[(f * GG + g_cur) * DD + lane], acc);
}
__global__ __launch_bounds__(256) void k_norm(float* outs, const float* counts) {
    int i = blockIdx.x * 256 + threadIdx.x;
    if (i < NFAC * GG * DD) {
        int g = (i >> 6) & (GG - 1);
        outs[i] /= fmaxf(counts[g], 1.f);
    }
}

// ---------------------------------------------------------------- launch
extern "C" void kernel_launch(void* const* d_in, const int* in_sizes, int n_in,
                              void* d_out, int out_size, void* d_ws, size_t ws_size,
                              hipStream_t stream) {
    const float* x    = (const float*)d_in[0];
    const int*   ei   = (const int*)d_in[1];
    const float* att  = (const float*)d_in[2];
    const int*   batch= (const int*)d_in[3];
    const float* linW = (const float*)d_in[4];
    const float* linb = (const float*)d_in[5];
    const float* wrel = (const float*)d_in[6];
    const float* brel = (const float*)d_in[7];
    const float* wroot= (const float*)d_in[8];
    const float* wih  = (const float*)d_in[9];
    const float* whh  = (const float*)d_in[10];
    const float* bih  = (const float*)d_in[11];
    const float* bhh  = (const float*)d_in[12];

    float* outs  = (float*)d_out;                 // [4,128,64]
    float* feats = (float*)d_out + NFAC * GG * DD; // [4,N,64]

    char* p = (char*)d_ws;
    unsigned short* out16 = (unsigned short*)p; p += (size_t)NFAC * NN * DD * 2;
    unsigned short* agg16 = (unsigned short*)p; p += (size_t)NFAC * NN * DD * 2;
    unsigned short* x16   = (unsigned short*)p; p += (size_t)NN * FDIM * 2;
    unsigned short* prep  = (unsigned short*)p; p += (size_t)PREP_TOTAL * 2;
    float4* csr_att4      = (float4*)p;         p += (size_t)EE * 16;
    int* csr_src          = (int*)p;            p += (size_t)EE * 4;
    int* deg              = (int*)p;            p += (size_t)NN * 4;
    int* cursor           = (int*)p;            p += (size_t)NN * 4;
    int* row_pos          = (int*)p;            p += (size_t)NN * 4;
    int* boff             = (int*)p;            p += 512 * 4;
    float* counts         = (float*)p;          p += 512;

    k_init <<<dim3(391),  dim3(256), 0, stream>>>(deg, cursor, counts, outs);
    k_prep <<<dim3(4096), dim3(256), 0, stream>>>(x, linW, wrel, wroot, wih, whh, x16, prep);
    k_count<<<dim3(391),  dim3(256), 0, stream>>>(batch, counts);
    k_deg  <<<dim3(6250), dim3(256), 0, stream>>>(ei, deg);
    k_scan1<<<dim3(391),  dim3(256), 0, stream>>>(deg, row_pos, boff);
    k_scan2<<<dim3(1),    dim3(512), 0, stream>>>(boff);
    k_fill <<<dim3(6250), dim3(256), 0, stream>>>(ei, att, row_pos, boff, cursor, csr_src, csr_att4);
    k_lin  <<<dim3(1563, 4), dim3(256), 0, stream>>>(x16, prep, linb, out16);
    for (int l = 0; l < NLAY; l++) {
        k_gather<<<dim3(25000),   dim3(256), 0, stream>>>(row_pos, boff, deg, csr_src, csr_att4, out16, agg16);
        k_layer <<<dim3(1563, 4), dim3(256), 0, stream>>>(l, agg16, out16, prep, brel, bih, bhh,
                                                          feats, (l == NLAY - 1) ? 1 : 0);
    }
    k_pool <<<dim3(391, 4), dim3(256), 0, stream>>>(feats, batch, outs);
    k_norm <<<dim3(128),    dim3(256), 0, stream>>>(outs, counts);
}

// Round 2
// 1366.050 us; speedup vs baseline: 1.2203x; 1.2203x over previous
//
#include <hip/hip_runtime.h>

#define NN   100000
#define EE   1600000
#define FDIM 128
#define NFAC 4
#define DD   64
#define NLAY 3
#define GG   128

// prep weight buffer layout (bf16 elems), per-factor stride:
#define PF_STRIDE 57344
#define OFF_WREL  8192
#define OFF_WROOT 20480
#define OFF_WIH   32768
#define OFF_WHH   45056
#define PREP_TOTAL (NFAC * PF_STRIDE)   // 229376

typedef __bf16 bf16x8_t __attribute__((ext_vector_type(8)));
typedef float  f32x4_t  __attribute__((ext_vector_type(4)));

__device__ __forceinline__ unsigned short f2bf(float x) {
    unsigned u = __float_as_uint(x);
    u += 0x7fffu + ((u >> 16) & 1u);        // round-to-nearest-even
    return (unsigned short)(u >> 16);
}
__device__ __forceinline__ float b2f(unsigned short h) {
    return __uint_as_float(((unsigned)h) << 16);
}
__device__ __forceinline__ float sigm(float x) { return 1.f / (1.f + __expf(-x)); }
__device__ __forceinline__ float tanh_f(float x) {
    float t = __expf(-2.f * fabsf(x));
    float r = (1.f - t) / (1.f + t);
    return x >= 0.f ? r : -r;
}

// ---------------------------------------------------------------- init
__global__ __launch_bounds__(256) void k_init(int* deg, int* cursor, float* outs) {
    int i = blockIdx.x * 256 + threadIdx.x;
    if (i < NN) { deg[i] = 0; cursor[i] = 0; }
    if (i < NFAC * GG * DD) outs[i] = 0.f;
}

// ------------------------------------------------- weight + x bf16 prep
// B-fragment order: for matrix B[k][n]: elem((nt*KB+kb)*64+lane)*8+j = B[kb*32+(lane>>4)*8+j][nt*16+(lane&15)]
__global__ __launch_bounds__(256) void k_prep(const float* x, const float* linW,
                                              const float* wrel, const float* wroot,
                                              const float* wih, const float* whh,
                                              unsigned short* x16, unsigned short* prep) {
    for (int i = blockIdx.x * 256 + threadIdx.x; i < NN * FDIM; i += gridDim.x * 256)
        x16[i] = f2bf(x[i]);
    for (int idx = blockIdx.x * 256 + threadIdx.x; idx < PREP_TOTAL; idx += gridDim.x * 256) {
        int f = idx / PF_STRIDE, r = idx % PF_STRIDE;
        int e, KB, mode, l = 0;
        if (r < OFF_WREL)       { e = r;                 KB = 4; mode = 0; }
        else if (r < OFF_WROOT) { int rr = r - OFF_WREL;  l = rr >> 12; e = rr & 4095; KB = 2; mode = 1; }
        else if (r < OFF_WIH)   { int rr = r - OFF_WROOT; l = rr >> 12; e = rr & 4095; KB = 2; mode = 2; }
        else if (r < OFF_WHH)   { e = r - OFF_WIH;        KB = 2; mode = 3; }
        else                    { e = r - OFF_WHH;        KB = 2; mode = 4; }
        int j = e & 7, lane = (e >> 3) & 63, t = e >> 9;
        int kb = t % KB, nt = t / KB;
        int k = kb * 32 + (lane >> 4) * 8 + j;
        int n = nt * 16 + (lane & 15);
        float v;
        if (mode == 0)      v = linW[(f * FDIM + k) * DD + n];
        else if (mode == 1) v = wrel[((f * 3 + l) * DD + k) * DD + n];
        else if (mode == 2) v = wroot[((f * 3 + l) * DD + k) * DD + n];
        else if (mode == 3) v = wih[(f * 192 + n) * DD + k];   // B = Wih^T
        else                v = whh[(f * 192 + n) * DD + k];
        prep[idx] = f2bf(v);
    }
}

// ---------------------------------------------------------------- counts: batch sorted -> binary search, no atomics
__global__ __launch_bounds__(256) void k_count(const int* batch, float* counts) {
    __shared__ int lb[GG + 1];
    int t = threadIdx.x;
    if (t <= GG) {
        int lo = 0, hi = NN;
        while (lo < hi) { int mid = (lo + hi) >> 1; if (batch[mid] < t) lo = mid + 1; else hi = mid; }
        lb[t] = lo;
    }
    __syncthreads();
    if (t < GG) counts[t] = (float)(lb[t + 1] - lb[t]);
}

// ---------------------------------------------------------------- CSR build
__global__ __launch_bounds__(256) void k_deg(const int* ei, int* deg) {
    int e = blockIdx.x * 256 + threadIdx.x;
    if (e < EE) atomicAdd(&deg[ei[EE + e]], 1);
}
__global__ __launch_bounds__(256) void k_scan1(const int* deg, int* row_pos, int* bsum) {
    __shared__ int lds[256];
    int tid = threadIdx.x, idx = blockIdx.x * 256 + tid;
    int v = (idx < NN) ? deg[idx] : 0;
    lds[tid] = v; __syncthreads();
    for (int s = 1; s < 256; s <<= 1) {
        int t = (tid >= s) ? lds[tid - s] : 0;
        __syncthreads();
        lds[tid] += t;
        __syncthreads();
    }
    if (idx < NN) row_pos[idx] = lds[tid] - v;   // exclusive within block
    if (tid == 255) bsum[blockIdx.x] = lds[255];
}
__global__ __launch_bounds__(512) void k_scan2(int* bsum) {  // 1 block, 512 threads, 391 valid
    __shared__ int lds[512];
    int tid = threadIdx.x;
    int v = (tid < 391) ? bsum[tid] : 0;
    lds[tid] = v; __syncthreads();
    for (int s = 1; s < 512; s <<= 1) {
        int t = (tid >= s) ? lds[tid - s] : 0;
        __syncthreads();
        lds[tid] += t;
        __syncthreads();
    }
    bsum[tid] = lds[tid] - v;                    // exclusive block offsets
}
__global__ __launch_bounds__(256) void k_fill(const int* ei, const float* att,
                                              const int* row_pos, const int* boff, int* cursor,
                                              int* csr_src, float4* csr_att4) {
    int e = blockIdx.x * 256 + threadIdx.x;
    if (e >= EE) return;
    int d = ei[EE + e];
    int slot = row_pos[d] + boff[d >> 8] + atomicAdd(&cursor[d], 1);
    csr_src[slot] = ei[e];
    csr_att4[slot] = make_float4(att[e], att[EE + e], att[2 * EE + e], att[3 * EE + e]);
}

// ---------------------------------------------------------------- lin: out16[f] = bf16(x @ linW[f] + b[f])
__global__ __launch_bounds__(256) void k_lin(const unsigned short* x16, const unsigned short* prep,
                                             const float* linb, unsigned short* out16) {
    int f = blockIdx.y, n0 = blockIdx.x * 64;
    __shared__ unsigned short xs[64 * 136];      // 128 cols + 8 pad
    int tid = threadIdx.x;
    for (int t = tid; t < 1024; t += 256) {      // 64 rows x 16 segs x 8 elems
        int row = t >> 4, seg = t & 15;
        int gn = n0 + row; if (gn >= NN) gn = NN - 1;
        *(uint4*)(xs + row * 136 + seg * 8) = *(const uint4*)(x16 + gn * FDIM + seg * 8);
    }
    __syncthreads();
    int w = tid >> 6, lane = tid & 63, mrow = lane & 15, q = lane >> 4;
    const unsigned short* wp = prep + f * PF_STRIDE;
#pragma unroll
    for (int nt = 0; nt < 4; nt++) {
        f32x4_t acc = {0.f, 0.f, 0.f, 0.f};
#pragma unroll
        for (int kb = 0; kb < 4; kb++) {
            bf16x8_t a = *(const bf16x8_t*)(xs + (w * 16 + mrow) * 136 + kb * 32 + q * 8);
            bf16x8_t b = *(const bf16x8_t*)(wp + ((nt * 4 + kb) * 64 + lane) * 8);
            acc = __builtin_amdgcn_mfma_f32_16x16x32_bf16(a, b, acc, 0, 0, 0);
        }
        int col = nt * 16 + mrow;
        float bias = linb[f * DD + col];
#pragma unroll
        for (int r = 0; r < 4; r++) {
            int node = n0 + w * 16 + q * 4 + r;
            if (node < NN) out16[((size_t)f * NN + node) * DD + col] = f2bf(acc[r] + bias);
        }
    }
}

// ---------------------------------------------------------------- gather: agg16[f][n] = sum_e att[f][e]*out16[f][src]
__global__ __launch_bounds__(256) void k_gather(const int* row_pos, const int* boff, const int* deg,
                                                const int* csr_src, const float4* csr_att4,
                                                const unsigned short* out16, unsigned short* agg16) {
    int wave = threadIdx.x >> 6, lane = threadIdx.x & 63;
    int n = blockIdx.x * 4 + wave;
    if (n >= NN) return;
    int row = row_pos[n] + boff[n >> 8];
    int dg = deg[n];
    float a0 = 0.f, a1 = 0.f, a2 = 0.f, a3 = 0.f;
    int s_nxt = 0; float4 at_nxt = make_float4(0.f, 0.f, 0.f, 0.f);
    if (dg > 0) { s_nxt = csr_src[row]; at_nxt = csr_att4[row]; }
    for (int i = 0; i < dg; i++) {
        int s = s_nxt; float4 at = at_nxt;
        if (i + 1 < dg) { s_nxt = csr_src[row + i + 1]; at_nxt = csr_att4[row + i + 1]; }
        int base = s * DD + lane;
        float v0 = b2f(out16[(size_t)0 * NN * DD + base]);
        float v1 = b2f(out16[(size_t)1 * NN * DD + base]);
        float v2 = b2f(out16[(size_t)2 * NN * DD + base]);
        float v3 = b2f(out16[(size_t)3 * NN * DD + base]);
        a0 += at.x * v0; a1 += at.y * v1; a2 += at.z * v2; a3 += at.w * v3;
    }
    agg16[((size_t)0 * NN + n) * DD + lane] = f2bf(a0);
    agg16[((size_t)1 * NN + n) * DD + lane] = f2bf(a1);
    agg16[((size_t)2 * NN + n) * DD + lane] = f2bf(a2);
    agg16[((size_t)3 * NN + n) * DD + lane] = f2bf(a3);
}

// ---------------------------------------------------------------- fused layer: m = relu(agg@Wrel + out@Wroot + brel); h' = GRU(m, h=out)
__global__ __launch_bounds__(256) void k_layer(int l, const unsigned short* agg16, unsigned short* out16,
                                               const unsigned short* prep, const float* brel,
                                               const float* bih, const float* bhh,
                                               float* feats, int last) {
    int f = blockIdx.y, n0 = blockIdx.x * 64;
    __shared__ unsigned short A1[64 * 72];   // agg tile (pad 64->72)
    __shared__ unsigned short A2[64 * 72];   // out (=h) tile
    __shared__ unsigned short Mt[64 * 72];   // m tile
    int tid = threadIdx.x;
    for (int t = tid; t < 512; t += 256) {   // 64 rows x 8 segs x 8 elems
        int row = t >> 3, seg = t & 7;
        int gn = n0 + row; if (gn >= NN) gn = NN - 1;
        *(uint4*)(A1 + row * 72 + seg * 8) = *(const uint4*)(agg16 + ((size_t)f * NN + gn) * DD + seg * 8);
        *(uint4*)(A2 + row * 72 + seg * 8) = *(const uint4*)(out16 + ((size_t)f * NN + gn) * DD + seg * 8);
    }
    __syncthreads();
    int w = tid >> 6, lane = tid & 63, mrow = lane & 15, q = lane >> 4;
    const unsigned short* wrel  = prep + f * PF_STRIDE + OFF_WREL  + l * 4096;
    const unsigned short* wroot = prep + f * PF_STRIDE + OFF_WROOT + l * 4096;

    // phase 1: m
#pragma unroll
    for (int nt = 0; nt < 4; nt++) {
        f32x4_t acc = {0.f, 0.f, 0.f, 0.f};
#pragma unroll
        for (int kb = 0; kb < 2; kb++) {
            bf16x8_t a1 = *(const bf16x8_t*)(A1 + (w * 16 + mrow) * 72 + kb * 32 + q * 8);
            bf16x8_t b1 = *(const bf16x8_t*)(wrel + ((nt * 2 + kb) * 64 + lane) * 8);
            acc = __builtin_amdgcn_mfma_f32_16x16x32_bf16(a1, b1, acc, 0, 0, 0);
            bf16x8_t a2 = *(const bf16x8_t*)(A2 + (w * 16 + mrow) * 72 + kb * 32 + q * 8);
            bf16x8_t b2 = *(const bf16x8_t*)(wroot + ((nt * 2 + kb) * 64 + lane) * 8);
            acc = __builtin_amdgcn_mfma_f32_16x16x32_bf16(a2, b2, acc, 0, 0, 0);
        }
        int col = nt * 16 + mrow;
        float bias = brel[(f * 3 + l) * DD + col];
#pragma unroll
        for (int r = 0; r < 4; r++) {
            float mv = acc[r] + bias;
            mv = mv > 0.f ? mv : 0.f;
            Mt[(w * 16 + q * 4 + r) * 72 + col] = f2bf(mv);
        }
    }
    __syncthreads();

    // phase 2: gi = m@Wih^T, gh = h@Whh^T  (192 cols = 12 n-tiles)
    const unsigned short* wih = prep + f * PF_STRIDE + OFF_WIH;
    const unsigned short* whh = prep + f * PF_STRIDE + OFF_WHH;
    float g1[12][4], g2[12][4];
#pragma unroll
    for (int nt = 0; nt < 12; nt++) {
        f32x4_t acc1 = {0.f, 0.f, 0.f, 0.f}, acc2 = {0.f, 0.f, 0.f, 0.f};
#pragma unroll
        for (int kb = 0; kb < 2; kb++) {
            bf16x8_t am = *(const bf16x8_t*)(Mt + (w * 16 + mrow) * 72 + kb * 32 + q * 8);
            bf16x8_t bi = *(const bf16x8_t*)(wih + ((nt * 2 + kb) * 64 + lane) * 8);
            acc1 = __builtin_amdgcn_mfma_f32_16x16x32_bf16(am, bi, acc1, 0, 0, 0);
            bf16x8_t ah = *(const bf16x8_t*)(A2 + (w * 16 + mrow) * 72 + kb * 32 + q * 8);
            bf16x8_t bh = *(const bf16x8_t*)(whh + ((nt * 2 + kb) * 64 + lane) * 8);
            acc2 = __builtin_amdgcn_mfma_f32_16x16x32_bf16(ah, bh, acc2, 0, 0, 0);
        }
#pragma unroll
        for (int r = 0; r < 4; r++) { g1[nt][r] = acc1[r]; g2[nt][r] = acc2[r]; }
    }

    // gates
#pragma unroll
    for (int nt = 0; nt < 4; nt++) {
        int col = nt * 16 + mrow;
        float bi_r = bih[f * 192 + col],        bh_r = bhh[f * 192 + col];
        float bi_z = bih[f * 192 + 64 + col],   bh_z = bhh[f * 192 + 64 + col];
        float bi_n = bih[f * 192 + 128 + col],  bh_n = bhh[f * 192 + 128 + col];
#pragma unroll
        for (int r = 0; r < 4; r++) {
            float ir = g1[nt][r] + bi_r,      hr = g2[nt][r] + bh_r;
            float iz = g1[nt + 4][r] + bi_z,  hz = g2[nt + 4][r] + bh_z;
            float in_ = g1[nt + 8][r] + bi_n, hn = g2[nt + 8][r] + bh_n;
            float rg = sigm(ir + hr);
            float z  = sigm(iz + hz);
            float nn = tanh_f(in_ + rg * hn);
            float h  = b2f(A2[(w * 16 + q * 4 + r) * 72 + col]);
            float hp = (1.f - z) * nn + z * h;
            int node = n0 + w * 16 + q * 4 + r;
            if (node < NN) {
                out16[((size_t)f * NN + node) * DD + col] = f2bf(hp);
                if (last) feats[((size_t)f * NN + node) * DD + col] = hp;
            }
        }
    }
}

// ---------------------------------------------------------------- pool (batch is sorted -> segmented reduce, few atomics)
__global__ __launch_bounds__(256) void k_pool(const float* feats, const int* batch, float* outs) {
    int f = blockIdx.y, w = threadIdx.x >> 6, lane = threadIdx.x & 63;
    int nbase = blockIdx.x * 256 + w * 64;
    if (nbase >= NN) return;
    int g_cur = batch[nbase];
    float acc = 0.f;
    for (int i = 0; i < 64; i++) {
        int n = nbase + i;
        if (n >= NN) break;
        int g = batch[n];
        float v = feats[((size_t)f * NN + n) * DD + lane];
        if (g != g_cur) {
            atomicAdd(&outs[(f * GG + g_cur) * DD + lane], acc);
            acc = v; g_cur = g;
        } else acc += v;
    }
    atomicAdd(&outs[(f * GG + g_cur) * DD + lane], acc);
}
__global__ __launch_bounds__(256) void k_norm(float* outs, const float* counts) {
    int i = blockIdx.x * 256 + threadIdx.x;
    if (i < NFAC * GG * DD) {
        int g = (i >> 6) & (GG - 1);
        outs[i] /= fmaxf(counts[g], 1.f);
    }
}

// ---------------------------------------------------------------- launch
extern "C" void kernel_launch(void* const* d_in, const int* in_sizes, int n_in,
                              void* d_out, int out_size, void* d_ws, size_t ws_size,
                              hipStream_t stream) {
    const float* x    = (const float*)d_in[0];
    const int*   ei   = (const int*)d_in[1];
    const float* att  = (const float*)d_in[2];
    const int*   batch= (const int*)d_in[3];
    const float* linW = (const float*)d_in[4];
    const float* linb = (const float*)d_in[5];
    const float* wrel = (const float*)d_in[6];
    const float* brel = (const float*)d_in[7];
    const float* wroot= (const float*)d_in[8];
    const float* wih  = (const float*)d_in[9];
    const float* whh  = (const float*)d_in[10];
    const float* bih  = (const float*)d_in[11];
    const float* bhh  = (const float*)d_in[12];

    float* outs  = (float*)d_out;                 // [4,128,64]
    float* feats = (float*)d_out + NFAC * GG * DD; // [4,N,64]

    char* p = (char*)d_ws;
    unsigned short* out16 = (unsigned short*)p; p += (size_t)NFAC * NN * DD * 2;
    unsigned short* agg16 = (unsigned short*)p; p += (size_t)NFAC * NN * DD * 2;
    unsigned short* x16   = (unsigned short*)p; p += (size_t)NN * FDIM * 2;
    unsigned short* prep  = (unsigned short*)p; p += (size_t)PREP_TOTAL * 2;
    float4* csr_att4      = (float4*)p;         p += (size_t)EE * 16;
    int* csr_src          = (int*)p;            p += (size_t)EE * 4;
    int* deg              = (int*)p;            p += (size_t)NN * 4;
    int* cursor           = (int*)p;            p += (size_t)NN * 4;
    int* row_pos          = (int*)p;            p += (size_t)NN * 4;
    int* boff             = (int*)p;            p += 512 * 4;
    float* counts         = (float*)p;          p += 512;

    k_init <<<dim3(391),  dim3(256), 0, stream>>>(deg, cursor, outs);
    k_prep <<<dim3(4096), dim3(256), 0, stream>>>(x, linW, wrel, wroot, wih, whh, x16, prep);
    k_count<<<dim3(1),    dim3(256), 0, stream>>>(batch, counts);
    k_deg  <<<dim3(6250), dim3(256), 0, stream>>>(ei, deg);
    k_scan1<<<dim3(391),  dim3(256), 0, stream>>>(deg, row_pos, boff);
    k_scan2<<<dim3(1),    dim3(512), 0, stream>>>(boff);
    k_fill <<<dim3(6250), dim3(256), 0, stream>>>(ei, att, row_pos, boff, cursor, csr_src, csr_att4);
    k_lin  <<<dim3(1563, 4), dim3(256), 0, stream>>>(x16, prep, linb, out16);
    for (int l = 0; l < NLAY; l++) {
        k_gather<<<dim3(25000),   dim3(256), 0, stream>>>(row_pos, boff, deg, csr_src, csr_att4, out16, agg16);
        k_layer <<<dim3(1563, 4), dim3(256), 0, stream>>>(l, agg16, out16, prep, brel, bih, bhh,
                                                          feats, (l == NLAY - 1) ? 1 : 0);
    }
    k_pool <<<dim3(391, 4), dim3(256), 0, stream>>>(feats, batch, outs);
    k_norm <<<dim3(128),    dim3(256), 0, stream>>>(outs, counts);
}

// Round 3
// 1046.840 us; speedup vs baseline: 1.5924x; 1.3049x over previous
//
#include <hip/hip_runtime.h>

#define NN   100000
#define EE   1600000
#define FDIM 128
#define NFAC 4
#define DD   64
#define NLAY 3
#define GG   128
#define ROW  (NFAC * DD)   // 256 elems = 512 B per node row, interleaved [n][f][d]

// prep weight buffer layout (bf16 elems), per-factor stride:
#define PF_STRIDE 57344
#define OFF_WREL  8192
#define OFF_WROOT 20480
#define OFF_WIH   32768
#define OFF_WHH   45056
#define PREP_TOTAL (NFAC * PF_STRIDE)   // 229376

typedef __bf16 bf16x8_t __attribute__((ext_vector_type(8)));
typedef float  f32x4_t  __attribute__((ext_vector_type(4)));

__device__ __forceinline__ unsigned short f2bf(float x) {
    unsigned u = __float_as_uint(x);
    u += 0x7fffu + ((u >> 16) & 1u);        // round-to-nearest-even
    return (unsigned short)(u >> 16);
}
__device__ __forceinline__ float b2f(unsigned short h) {
    return __uint_as_float(((unsigned)h) << 16);
}
__device__ __forceinline__ float sigm(float x) { return 1.f / (1.f + __expf(-x)); }
__device__ __forceinline__ float tanh_f(float x) {
    float t = __expf(-2.f * fabsf(x));
    float r = (1.f - t) / (1.f + t);
    return x >= 0.f ? r : -r;
}

// ---------------------------------------------------------------- init
__global__ __launch_bounds__(256) void k_init(int* deg, int* cursor, float* outs) {
    int i = blockIdx.x * 256 + threadIdx.x;
    if (i < NN) { deg[i] = 0; cursor[i] = 0; }
    if (i < NFAC * GG * DD) outs[i] = 0.f;
}

// ------------------------------------------------- weight + x bf16 prep
// B-fragment order: for matrix B[k][n]: elem((nt*KB+kb)*64+lane)*8+j = B[kb*32+(lane>>4)*8+j][nt*16+(lane&15)]
__global__ __launch_bounds__(256) void k_prep(const float* x, const float* linW,
                                              const float* wrel, const float* wroot,
                                              const float* wih, const float* whh,
                                              unsigned short* x16, unsigned short* prep) {
    for (int i = blockIdx.x * 256 + threadIdx.x; i < NN * FDIM; i += gridDim.x * 256)
        x16[i] = f2bf(x[i]);
    for (int idx = blockIdx.x * 256 + threadIdx.x; idx < PREP_TOTAL; idx += gridDim.x * 256) {
        int f = idx / PF_STRIDE, r = idx % PF_STRIDE;
        int e, KB, mode, l = 0;
        if (r < OFF_WREL)       { e = r;                 KB = 4; mode = 0; }
        else if (r < OFF_WROOT) { int rr = r - OFF_WREL;  l = rr >> 12; e = rr & 4095; KB = 2; mode = 1; }
        else if (r < OFF_WIH)   { int rr = r - OFF_WROOT; l = rr >> 12; e = rr & 4095; KB = 2; mode = 2; }
        else if (r < OFF_WHH)   { e = r - OFF_WIH;        KB = 2; mode = 3; }
        else                    { e = r - OFF_WHH;        KB = 2; mode = 4; }
        int j = e & 7, lane = (e >> 3) & 63, t = e >> 9;
        int kb = t % KB, nt = t / KB;
        int k = kb * 32 + (lane >> 4) * 8 + j;
        int n = nt * 16 + (lane & 15);
        float v;
        if (mode == 0)      v = linW[(f * FDIM + k) * DD + n];
        else if (mode == 1) v = wrel[((f * 3 + l) * DD + k) * DD + n];
        else if (mode == 2) v = wroot[((f * 3 + l) * DD + k) * DD + n];
        else if (mode == 3) v = wih[(f * 192 + n) * DD + k];   // B = Wih^T
        else                v = whh[(f * 192 + n) * DD + k];
        prep[idx] = f2bf(v);
    }
}

// ---------------------------------------------------------------- counts: batch sorted -> binary search, no atomics
__global__ __launch_bounds__(256) void k_count(const int* batch, float* counts) {
    __shared__ int lb[GG + 1];
    int t = threadIdx.x;
    if (t <= GG) {
        int lo = 0, hi = NN;
        while (lo < hi) { int mid = (lo + hi) >> 1; if (batch[mid] < t) lo = mid + 1; else hi = mid; }
        lb[t] = lo;
    }
    __syncthreads();
    if (t < GG) counts[t] = (float)(lb[t + 1] - lb[t]);
}

// ---------------------------------------------------------------- CSR build
__global__ __launch_bounds__(256) void k_deg(const int* ei, int* deg) {
    int e = blockIdx.x * 256 + threadIdx.x;
    if (e < EE) atomicAdd(&deg[ei[EE + e]], 1);
}
__global__ __launch_bounds__(256) void k_scan1(const int* deg, int* row_pos, int* bsum) {
    __shared__ int lds[256];
    int tid = threadIdx.x, idx = blockIdx.x * 256 + tid;
    int v = (idx < NN) ? deg[idx] : 0;
    lds[tid] = v; __syncthreads();
    for (int s = 1; s < 256; s <<= 1) {
        int t = (tid >= s) ? lds[tid - s] : 0;
        __syncthreads();
        lds[tid] += t;
        __syncthreads();
    }
    if (idx < NN) row_pos[idx] = lds[tid] - v;   // exclusive within block
    if (tid == 255) bsum[blockIdx.x] = lds[255];
}
__global__ __launch_bounds__(512) void k_scan2(int* bsum) {  // 1 block, 512 threads, 391 valid
    __shared__ int lds[512];
    int tid = threadIdx.x;
    int v = (tid < 391) ? bsum[tid] : 0;
    lds[tid] = v; __syncthreads();
    for (int s = 1; s < 512; s <<= 1) {
        int t = (tid >= s) ? lds[tid - s] : 0;
        __syncthreads();
        lds[tid] += t;
        __syncthreads();
    }
    bsum[tid] = lds[tid] - v;                    // exclusive block offsets
}
__global__ __launch_bounds__(256) void k_rowptr(const int* row_pos, const int* boff, int* row_ptr) {
    int i = blockIdx.x * 256 + threadIdx.x;
    if (i < NN) row_ptr[i] = row_pos[i] + boff[i >> 8];
    if (i == 0) row_ptr[NN] = EE;
}
__global__ __launch_bounds__(256) void k_fill(const int* ei, const float* att,
                                              const int* row_ptr, int* cursor,
                                              int* csr_src, float* csr_att) {
    int e = blockIdx.x * 256 + threadIdx.x;
    if (e >= EE) return;
    int d = ei[EE + e];
    int slot = row_ptr[d] + atomicAdd(&cursor[d], 1);
    csr_src[slot] = ei[e];
    *(float4*)(csr_att + (size_t)slot * 4) =
        make_float4(att[e], att[EE + e], att[2 * EE + e], att[3 * EE + e]);
}

// ---------------------------------------------------------------- lin: out16[n][f] = bf16(x @ linW[f] + b[f])
__global__ __launch_bounds__(256) void k_lin(const unsigned short* x16, const unsigned short* prep,
                                             const float* linb, unsigned short* out16) {
    int f = blockIdx.y, n0 = blockIdx.x * 64;
    __shared__ unsigned short xs[64 * 136];      // 128 cols + 8 pad
    int tid = threadIdx.x;
    for (int t = tid; t < 1024; t += 256) {      // 64 rows x 16 segs x 8 elems
        int row = t >> 4, seg = t & 15;
        int gn = n0 + row; if (gn >= NN) gn = NN - 1;
        *(uint4*)(xs + row * 136 + seg * 8) = *(const uint4*)(x16 + gn * FDIM + seg * 8);
    }
    __syncthreads();
    int w = tid >> 6, lane = tid & 63, mrow = lane & 15, q = lane >> 4;
    const unsigned short* wp = prep + f * PF_STRIDE;
#pragma unroll
    for (int nt = 0; nt < 4; nt++) {
        f32x4_t acc = {0.f, 0.f, 0.f, 0.f};
#pragma unroll
        for (int kb = 0; kb < 4; kb++) {
            bf16x8_t a = *(const bf16x8_t*)(xs + (w * 16 + mrow) * 136 + kb * 32 + q * 8);
            bf16x8_t b = *(const bf16x8_t*)(wp + ((nt * 4 + kb) * 64 + lane) * 8);
            acc = __builtin_amdgcn_mfma_f32_16x16x32_bf16(a, b, acc, 0, 0, 0);
        }
        int col = nt * 16 + mrow;
        float bias = linb[f * DD + col];
#pragma unroll
        for (int r = 0; r < 4; r++) {
            int node = n0 + w * 16 + q * 4 + r;
            if (node < NN) out16[(size_t)node * ROW + f * DD + col] = f2bf(acc[r] + bias);
        }
    }
}

// ---------------------------------------------------------------- gather (interleaved rows):
// lane L covers factor L>>4, dims 4*(L&15)..+3; one uint2 load = whole wave reads the 512B src row
__global__ __launch_bounds__(256) void k_gather(const int* row_ptr, const int* csr_src, const float* csr_att,
                                                const unsigned short* out16, unsigned short* agg16) {
    int wave = threadIdx.x >> 6, lane = threadIdx.x & 63;
    int n = blockIdx.x * 4 + wave;
    if (n >= NN) return;
    int row = row_ptr[n], end = row_ptr[n + 1];
    int fsel = lane >> 4, loff = lane * 4;
    float a0 = 0.f, a1 = 0.f, a2 = 0.f, a3 = 0.f;
    int i = row;
    for (; i + 4 <= end; i += 4) {
        int s0 = csr_src[i], s1 = csr_src[i + 1], s2 = csr_src[i + 2], s3 = csr_src[i + 3];
        float w0 = csr_att[(size_t)(i)     * 4 + fsel];
        float w1 = csr_att[(size_t)(i + 1) * 4 + fsel];
        float w2 = csr_att[(size_t)(i + 2) * 4 + fsel];
        float w3 = csr_att[(size_t)(i + 3) * 4 + fsel];
        uint2 v0 = *(const uint2*)(out16 + (size_t)s0 * ROW + loff);
        uint2 v1 = *(const uint2*)(out16 + (size_t)s1 * ROW + loff);
        uint2 v2 = *(const uint2*)(out16 + (size_t)s2 * ROW + loff);
        uint2 v3 = *(const uint2*)(out16 + (size_t)s3 * ROW + loff);
        a0 = fmaf(w0, __uint_as_float(v0.x << 16), a0);
        a1 = fmaf(w0, __uint_as_float(v0.x & 0xffff0000u), a1);
        a2 = fmaf(w0, __uint_as_float(v0.y << 16), a2);
        a3 = fmaf(w0, __uint_as_float(v0.y & 0xffff0000u), a3);
        a0 = fmaf(w1, __uint_as_float(v1.x << 16), a0);
        a1 = fmaf(w1, __uint_as_float(v1.x & 0xffff0000u), a1);
        a2 = fmaf(w1, __uint_as_float(v1.y << 16), a2);
        a3 = fmaf(w1, __uint_as_float(v1.y & 0xffff0000u), a3);
        a0 = fmaf(w2, __uint_as_float(v2.x << 16), a0);
        a1 = fmaf(w2, __uint_as_float(v2.x & 0xffff0000u), a1);
        a2 = fmaf(w2, __uint_as_float(v2.y << 16), a2);
        a3 = fmaf(w2, __uint_as_float(v2.y & 0xffff0000u), a3);
        a0 = fmaf(w3, __uint_as_float(v3.x << 16), a0);
        a1 = fmaf(w3, __uint_as_float(v3.x & 0xffff0000u), a1);
        a2 = fmaf(w3, __uint_as_float(v3.y << 16), a2);
        a3 = fmaf(w3, __uint_as_float(v3.y & 0xffff0000u), a3);
    }
    for (; i < end; i++) {
        int s = csr_src[i];
        float w = csr_att[(size_t)i * 4 + fsel];
        uint2 v = *(const uint2*)(out16 + (size_t)s * ROW + loff);
        a0 = fmaf(w, __uint_as_float(v.x << 16), a0);
        a1 = fmaf(w, __uint_as_float(v.x & 0xffff0000u), a1);
        a2 = fmaf(w, __uint_as_float(v.y << 16), a2);
        a3 = fmaf(w, __uint_as_float(v.y & 0xffff0000u), a3);
    }
    ushort4 r;
    r.x = f2bf(a0); r.y = f2bf(a1); r.z = f2bf(a2); r.w = f2bf(a3);
    *(ushort4*)(agg16 + (size_t)n * ROW + loff) = r;
}

// ---------------------------------------------------------------- fused layer: m = relu(agg@Wrel + out@Wroot + brel); h' = GRU(m, h=out)
__global__ __launch_bounds__(256) void k_layer(int l, const unsigned short* agg16, unsigned short* out16,
                                               const unsigned short* prep, const float* brel,
                                               const float* bih, const float* bhh,
                                               float* feats, int last) {
    int f = blockIdx.y, n0 = blockIdx.x * 64;
    __shared__ unsigned short A1[64 * 72];   // agg tile (pad 64->72)
    __shared__ unsigned short A2[64 * 72];   // out (=h) tile
    __shared__ unsigned short Mt[64 * 72];   // m tile
    int tid = threadIdx.x;
    for (int t = tid; t < 512; t += 256) {   // 64 rows x 8 segs x 8 elems
        int row = t >> 3, seg = t & 7;
        int gn = n0 + row; if (gn >= NN) gn = NN - 1;
        *(uint4*)(A1 + row * 72 + seg * 8) = *(const uint4*)(agg16 + (size_t)gn * ROW + f * DD + seg * 8);
        *(uint4*)(A2 + row * 72 + seg * 8) = *(const uint4*)(out16 + (size_t)gn * ROW + f * DD + seg * 8);
    }
    __syncthreads();
    int w = tid >> 6, lane = tid & 63, mrow = lane & 15, q = lane >> 4;
    const unsigned short* wrel  = prep + f * PF_STRIDE + OFF_WREL  + l * 4096;
    const unsigned short* wroot = prep + f * PF_STRIDE + OFF_WROOT + l * 4096;

    // phase 1: m
#pragma unroll
    for (int nt = 0; nt < 4; nt++) {
        f32x4_t acc = {0.f, 0.f, 0.f, 0.f};
#pragma unroll
        for (int kb = 0; kb < 2; kb++) {
            bf16x8_t a1 = *(const bf16x8_t*)(A1 + (w * 16 + mrow) * 72 + kb * 32 + q * 8);
            bf16x8_t b1 = *(const bf16x8_t*)(wrel + ((nt * 2 + kb) * 64 + lane) * 8);
            acc = __builtin_amdgcn_mfma_f32_16x16x32_bf16(a1, b1, acc, 0, 0, 0);
            bf16x8_t a2 = *(const bf16x8_t*)(A2 + (w * 16 + mrow) * 72 + kb * 32 + q * 8);
            bf16x8_t b2 = *(const bf16x8_t*)(wroot + ((nt * 2 + kb) * 64 + lane) * 8);
            acc = __builtin_amdgcn_mfma_f32_16x16x32_bf16(a2, b2, acc, 0, 0, 0);
        }
        int col = nt * 16 + mrow;
        float bias = brel[(f * 3 + l) * DD + col];
#pragma unroll
        for (int r = 0; r < 4; r++) {
            float mv = acc[r] + bias;
            mv = mv > 0.f ? mv : 0.f;
            Mt[(w * 16 + q * 4 + r) * 72 + col] = f2bf(mv);
        }
    }
    __syncthreads();

    // phase 2: per col-tile nt, compute r/z/n gates (cols nt*16, +64, +128) for gi and gh together
    const unsigned short* wih = prep + f * PF_STRIDE + OFF_WIH;
    const unsigned short* whh = prep + f * PF_STRIDE + OFF_WHH;
#pragma unroll
    for (int nt = 0; nt < 4; nt++) {
        f32x4_t ir = {0.f,0.f,0.f,0.f}, iz = {0.f,0.f,0.f,0.f}, in_ = {0.f,0.f,0.f,0.f};
        f32x4_t hr = {0.f,0.f,0.f,0.f}, hz = {0.f,0.f,0.f,0.f}, hn  = {0.f,0.f,0.f,0.f};
#pragma unroll
        for (int kb = 0; kb < 2; kb++) {
            bf16x8_t am = *(const bf16x8_t*)(Mt + (w * 16 + mrow) * 72 + kb * 32 + q * 8);
            bf16x8_t ah = *(const bf16x8_t*)(A2 + (w * 16 + mrow) * 72 + kb * 32 + q * 8);
            bf16x8_t br = *(const bf16x8_t*)(wih + (((nt)     * 2 + kb) * 64 + lane) * 8);
            bf16x8_t bz = *(const bf16x8_t*)(wih + (((nt + 4) * 2 + kb) * 64 + lane) * 8);
            bf16x8_t bn = *(const bf16x8_t*)(wih + (((nt + 8) * 2 + kb) * 64 + lane) * 8);
            ir = __builtin_amdgcn_mfma_f32_16x16x32_bf16(am, br, ir, 0, 0, 0);
            iz = __builtin_amdgcn_mfma_f32_16x16x32_bf16(am, bz, iz, 0, 0, 0);
            in_ = __builtin_amdgcn_mfma_f32_16x16x32_bf16(am, bn, in_, 0, 0, 0);
            bf16x8_t cr = *(const bf16x8_t*)(whh + (((nt)     * 2 + kb) * 64 + lane) * 8);
            bf16x8_t cz = *(const bf16x8_t*)(whh + (((nt + 4) * 2 + kb) * 64 + lane) * 8);
            bf16x8_t cn = *(const bf16x8_t*)(whh + (((nt + 8) * 2 + kb) * 64 + lane) * 8);
            hr = __builtin_amdgcn_mfma_f32_16x16x32_bf16(ah, cr, hr, 0, 0, 0);
            hz = __builtin_amdgcn_mfma_f32_16x16x32_bf16(ah, cz, hz, 0, 0, 0);
            hn = __builtin_amdgcn_mfma_f32_16x16x32_bf16(ah, cn, hn, 0, 0, 0);
        }
        int col = nt * 16 + mrow;
        float bi_r = bih[f * 192 + col],        bh_r = bhh[f * 192 + col];
        float bi_z = bih[f * 192 + 64 + col],   bh_z = bhh[f * 192 + 64 + col];
        float bi_n = bih[f * 192 + 128 + col],  bh_n = bhh[f * 192 + 128 + col];
#pragma unroll
        for (int r = 0; r < 4; r++) {
            float rg = sigm(ir[r] + bi_r + hr[r] + bh_r);
            float z  = sigm(iz[r] + bi_z + hz[r] + bh_z);
            float nn = tanh_f(in_[r] + bi_n + rg * (hn[r] + bh_n));
            float h  = b2f(A2[(w * 16 + q * 4 + r) * 72 + col]);
            float hp = (1.f - z) * nn + z * h;
            int node = n0 + w * 16 + q * 4 + r;
            if (node < NN) {
                out16[(size_t)node * ROW + f * DD + col] = f2bf(hp);
                if (last) feats[((size_t)f * NN + node) * DD + col] = hp;
            }
        }
    }
}

// ---------------------------------------------------------------- pool (batch is sorted -> segmented reduce, few atomics)
__global__ __launch_bounds__(256) void k_pool(const float* feats, const int* batch, float* outs) {
    int f = blockIdx.y, w = threadIdx.x >> 6, lane = threadIdx.x & 63;
    int nbase = blockIdx.x * 256 + w * 64;
    if (nbase >= NN) return;
    int g_cur = batch[nbase];
    float acc = 0.f;
    for (int i = 0; i < 64; i++) {
        int n = nbase + i;
        if (n >= NN) break;
        int g = batch[n];
        float v = feats[((size_t)f * NN + n) * DD + lane];
        if (g != g_cur) {
            atomicAdd(&outs[(f * GG + g_cur) * DD + lane], acc);
            acc = v; g_cur = g;
        } else acc += v;
    }
    atomicAdd(&outs[(f * GG + g_cur) * DD + lane], acc);
}
__global__ __launch_bounds__(256) void k_norm(float* outs, const float* counts) {
    int i = blockIdx.x * 256 + threadIdx.x;
    if (i < NFAC * GG * DD) {
        int g = (i >> 6) & (GG - 1);
        outs[i] /= fmaxf(counts[g], 1.f);
    }
}

// ---------------------------------------------------------------- launch
extern "C" void kernel_launch(void* const* d_in, const int* in_sizes, int n_in,
                              void* d_out, int out_size, void* d_ws, size_t ws_size,
                              hipStream_t stream) {
    const float* x    = (const float*)d_in[0];
    const int*   ei   = (const int*)d_in[1];
    const float* att  = (const float*)d_in[2];
    const int*   batch= (const int*)d_in[3];
    const float* linW = (const float*)d_in[4];
    const float* linb = (const float*)d_in[5];
    const float* wrel = (const float*)d_in[6];
    const float* brel = (const float*)d_in[7];
    const float* wroot= (const float*)d_in[8];
    const float* wih  = (const float*)d_in[9];
    const float* whh  = (const float*)d_in[10];
    const float* bih  = (const float*)d_in[11];
    const float* bhh  = (const float*)d_in[12];

    float* outs  = (float*)d_out;                  // [4,128,64]
    float* feats = (float*)d_out + NFAC * GG * DD; // [4,N,64]

    char* p = (char*)d_ws;
    unsigned short* out16 = (unsigned short*)p; p += (size_t)NN * ROW * 2;
    unsigned short* agg16 = (unsigned short*)p; p += (size_t)NN * ROW * 2;
    unsigned short* x16   = (unsigned short*)p; p += (size_t)NN * FDIM * 2;
    unsigned short* prep  = (unsigned short*)p; p += (size_t)PREP_TOTAL * 2;
    float* csr_att        = (float*)p;          p += (size_t)EE * 16;
    int* csr_src          = (int*)p;            p += (size_t)EE * 4;
    int* deg              = (int*)p;            p += (size_t)NN * 4;
    int* cursor           = (int*)p;            p += (size_t)NN * 4;
    int* row_pos          = (int*)p;            p += (size_t)NN * 4;
    int* row_ptr          = (int*)p;            p += (size_t)(NN + 1) * 4;
    int* boff             = (int*)p;            p += 512 * 4;
    float* counts         = (float*)p;          p += 512;

    k_init  <<<dim3(391),  dim3(256), 0, stream>>>(deg, cursor, outs);
    k_prep  <<<dim3(4096), dim3(256), 0, stream>>>(x, linW, wrel, wroot, wih, whh, x16, prep);
    k_count <<<dim3(1),    dim3(256), 0, stream>>>(batch, counts);
    k_deg   <<<dim3(6250), dim3(256), 0, stream>>>(ei, deg);
    k_scan1 <<<dim3(391),  dim3(256), 0, stream>>>(deg, row_pos, boff);
    k_scan2 <<<dim3(1),    dim3(512), 0, stream>>>(boff);
    k_rowptr<<<dim3(391),  dim3(256), 0, stream>>>(row_pos, boff, row_ptr);
    k_fill  <<<dim3(6250), dim3(256), 0, stream>>>(ei, att, row_ptr, cursor, csr_src, csr_att);
    k_lin   <<<dim3(1563, 4), dim3(256), 0, stream>>>(x16, prep, linb, out16);
    for (int l = 0; l < NLAY; l++) {
        k_gather<<<dim3(25000),   dim3(256), 0, stream>>>(row_ptr, csr_src, csr_att, out16, agg16);
        k_layer <<<dim3(1563, 4), dim3(256), 0, stream>>>(l, agg16, out16, prep, brel, bih, bhh,
                                                          feats, (l == NLAY - 1) ? 1 : 0);
    }
    k_pool <<<dim3(391, 4), dim3(256), 0, stream>>>(feats, batch, outs);
    k_norm <<<dim3(128),    dim3(256), 0, stream>>>(outs, counts);
}

// Round 4
// 1044.013 us; speedup vs baseline: 1.5967x; 1.0027x over previous
//
#include <hip/hip_runtime.h>

#define NN   100000
#define EE   1600000
#define FDIM 128
#define NFAC 4
#define DD   64
#define NLAY 3
#define GG   128
#define ROW  (NFAC * DD)   // 256 elems = 512 B per node row, interleaved [n][f][d]

// prep weight buffer layout (bf16 elems), per-factor stride:
#define PF_STRIDE 57344
#define OFF_WREL  8192
#define OFF_WROOT 20480
#define OFF_WIH   32768
#define OFF_WHH   45056
#define PREP_TOTAL (NFAC * PF_STRIDE)   // 229376

typedef __bf16 bf16x8_t __attribute__((ext_vector_type(8)));
typedef float  f32x4_t  __attribute__((ext_vector_type(4)));

__device__ __forceinline__ unsigned short f2bf(float x) {
    unsigned u = __float_as_uint(x);
    u += 0x7fffu + ((u >> 16) & 1u);        // round-to-nearest-even
    return (unsigned short)(u >> 16);
}
__device__ __forceinline__ float b2f(unsigned short h) {
    return __uint_as_float(((unsigned)h) << 16);
}
__device__ __forceinline__ float sigm(float x) { return 1.f / (1.f + __expf(-x)); }
__device__ __forceinline__ float tanh_f(float x) {
    float t = __expf(-2.f * fabsf(x));
    float r = (1.f - t) / (1.f + t);
    return x >= 0.f ? r : -r;
}

// ---------------------------------------------------------------- init
__global__ __launch_bounds__(256) void k_init(int* deg, int* cursor, float* outs) {
    int i = blockIdx.x * 256 + threadIdx.x;
    if (i < NN) { deg[i] = 0; cursor[i] = 0; }
    if (i < NFAC * GG * DD) outs[i] = 0.f;
}

// ------------------------------------------------- weight + x bf16 prep
// B-fragment order: for matrix B[k][n]: elem((nt*KB+kb)*64+lane)*8+j = B[kb*32+(lane>>4)*8+j][nt*16+(lane&15)]
__global__ __launch_bounds__(256) void k_prep(const float* x, const float* linW,
                                              const float* wrel, const float* wroot,
                                              const float* wih, const float* whh,
                                              unsigned short* x16, unsigned short* prep) {
    for (int i = blockIdx.x * 256 + threadIdx.x; i < NN * FDIM; i += gridDim.x * 256)
        x16[i] = f2bf(x[i]);
    for (int idx = blockIdx.x * 256 + threadIdx.x; idx < PREP_TOTAL; idx += gridDim.x * 256) {
        int f = idx / PF_STRIDE, r = idx % PF_STRIDE;
        int e, KB, mode, l = 0;
        if (r < OFF_WREL)       { e = r;                 KB = 4; mode = 0; }
        else if (r < OFF_WROOT) { int rr = r - OFF_WREL;  l = rr >> 12; e = rr & 4095; KB = 2; mode = 1; }
        else if (r < OFF_WIH)   { int rr = r - OFF_WROOT; l = rr >> 12; e = rr & 4095; KB = 2; mode = 2; }
        else if (r < OFF_WHH)   { e = r - OFF_WIH;        KB = 2; mode = 3; }
        else                    { e = r - OFF_WHH;        KB = 2; mode = 4; }
        int j = e & 7, lane = (e >> 3) & 63, t = e >> 9;
        int kb = t % KB, nt = t / KB;
        int k = kb * 32 + (lane >> 4) * 8 + j;
        int n = nt * 16 + (lane & 15);
        float v;
        if (mode == 0)      v = linW[(f * FDIM + k) * DD + n];
        else if (mode == 1) v = wrel[((f * 3 + l) * DD + k) * DD + n];
        else if (mode == 2) v = wroot[((f * 3 + l) * DD + k) * DD + n];
        else if (mode == 3) v = wih[(f * 192 + n) * DD + k];   // B = Wih^T
        else                v = whh[(f * 192 + n) * DD + k];
        prep[idx] = f2bf(v);
    }
}

// ---------------------------------------------------------------- counts: batch sorted -> binary search, no atomics
__global__ __launch_bounds__(256) void k_count(const int* batch, float* counts) {
    __shared__ int lb[GG + 1];
    int t = threadIdx.x;
    if (t <= GG) {
        int lo = 0, hi = NN;
        while (lo < hi) { int mid = (lo + hi) >> 1; if (batch[mid] < t) lo = mid + 1; else hi = mid; }
        lb[t] = lo;
    }
    __syncthreads();
    if (t < GG) counts[t] = (float)(lb[t + 1] - lb[t]);
}

// ---------------------------------------------------------------- CSR build
__global__ __launch_bounds__(256) void k_deg(const int* ei, int* deg) {
    int e = blockIdx.x * 256 + threadIdx.x;
    if (e < EE) atomicAdd(&deg[ei[EE + e]], 1);
}
__global__ __launch_bounds__(256) void k_scan1(const int* deg, int* row_pos, int* bsum) {
    __shared__ int lds[256];
    int tid = threadIdx.x, idx = blockIdx.x * 256 + tid;
    int v = (idx < NN) ? deg[idx] : 0;
    lds[tid] = v; __syncthreads();
    for (int s = 1; s < 256; s <<= 1) {
        int t = (tid >= s) ? lds[tid - s] : 0;
        __syncthreads();
        lds[tid] += t;
        __syncthreads();
    }
    if (idx < NN) row_pos[idx] = lds[tid] - v;   // exclusive within block
    if (tid == 255) bsum[blockIdx.x] = lds[255];
}
__global__ __launch_bounds__(512) void k_scan2(int* bsum) {  // 1 block, 512 threads, 391 valid
    __shared__ int lds[512];
    int tid = threadIdx.x;
    int v = (tid < 391) ? bsum[tid] : 0;
    lds[tid] = v; __syncthreads();
    for (int s = 1; s < 512; s <<= 1) {
        int t = (tid >= s) ? lds[tid - s] : 0;
        __syncthreads();
        lds[tid] += t;
        __syncthreads();
    }
    bsum[tid] = lds[tid] - v;                    // exclusive block offsets
}
__global__ __launch_bounds__(256) void k_rowptr(const int* row_pos, const int* boff, int* row_ptr) {
    int i = blockIdx.x * 256 + threadIdx.x;
    if (i < NN) row_ptr[i] = row_pos[i] + boff[i >> 8];
    if (i == 0) row_ptr[NN] = EE;
}
__global__ __launch_bounds__(256) void k_fill(const int* ei, const float* att,
                                              const int* row_ptr, int* cursor,
                                              int* csr_src, float* csr_att) {
    int e = blockIdx.x * 256 + threadIdx.x;
    if (e >= EE) return;
    int d = ei[EE + e];
    int slot = row_ptr[d] + atomicAdd(&cursor[d], 1);
    csr_src[slot] = ei[e];
    *(float4*)(csr_att + (size_t)slot * 4) =
        make_float4(att[e], att[EE + e], att[2 * EE + e], att[3 * EE + e]);
}

// ---------------------------------------------------------------- lin: out16[n][f] = bf16(x @ linW[f] + b[f])
__global__ __launch_bounds__(256) void k_lin(const unsigned short* x16, const unsigned short* prep,
                                             const float* linb, unsigned short* out16) {
    int f = blockIdx.y, n0 = blockIdx.x * 64;
    __shared__ unsigned short xs[64 * 136];      // 128 cols + 8 pad
    int tid = threadIdx.x;
    for (int t = tid; t < 1024; t += 256) {      // 64 rows x 16 segs x 8 elems
        int row = t >> 4, seg = t & 15;
        int gn = n0 + row; if (gn >= NN) gn = NN - 1;
        *(uint4*)(xs + row * 136 + seg * 8) = *(const uint4*)(x16 + gn * FDIM + seg * 8);
    }
    __syncthreads();
    int w = tid >> 6, lane = tid & 63, mrow = lane & 15, q = lane >> 4;
    const unsigned short* wp = prep + f * PF_STRIDE;
#pragma unroll
    for (int nt = 0; nt < 4; nt++) {
        f32x4_t acc = {0.f, 0.f, 0.f, 0.f};
#pragma unroll
        for (int kb = 0; kb < 4; kb++) {
            bf16x8_t a = *(const bf16x8_t*)(xs + (w * 16 + mrow) * 136 + kb * 32 + q * 8);
            bf16x8_t b = *(const bf16x8_t*)(wp + ((nt * 4 + kb) * 64 + lane) * 8);
            acc = __builtin_amdgcn_mfma_f32_16x16x32_bf16(a, b, acc, 0, 0, 0);
        }
        int col = nt * 16 + mrow;
        float bias = linb[f * DD + col];
#pragma unroll
        for (int r = 0; r < 4; r++) {
            int node = n0 + w * 16 + q * 4 + r;
            if (node < NN) out16[(size_t)node * ROW + f * DD + col] = f2bf(acc[r] + bias);
        }
    }
}

// ---------------------------------------------------------------- gather (interleaved rows), 8-deep pipelined:
// lane L covers factor L>>4, dims 4*(L&15)..+3; one uint2 load = whole wave reads the 512B src row
__global__ __launch_bounds__(256) void k_gather(const int* row_ptr, const int* csr_src, const float* csr_att,
                                                const unsigned short* out16, unsigned short* agg16) {
    int wave = threadIdx.x >> 6, lane = threadIdx.x & 63;
    int n = blockIdx.x * 4 + wave;
    if (n >= NN) return;
    int row = row_ptr[n], end = row_ptr[n + 1];
    int total = end - row;
    int fsel = lane >> 4, loff = lane * 4;
    float a0 = 0.f, a1 = 0.f, a2 = 0.f, a3 = 0.f;
    for (int base = 0; base < total; base += 8) {
        int s[8]; float w[8];
#pragma unroll
        for (int j = 0; j < 8; j++) {
            int e = base + j;
            int idx = row + (e < total ? e : total - 1);   // clamped pad -> cached line, w=0
            s[j] = csr_src[idx];
            float ww = csr_att[(size_t)idx * 4 + fsel];
            w[j] = (e < total) ? ww : 0.f;
        }
        uint2 v[8];
#pragma unroll
        for (int j = 0; j < 8; j++)
            v[j] = *(const uint2*)(out16 + (size_t)s[j] * ROW + loff);
#pragma unroll
        for (int j = 0; j < 8; j++) {
            a0 = fmaf(w[j], __uint_as_float(v[j].x << 16), a0);
            a1 = fmaf(w[j], __uint_as_float(v[j].x & 0xffff0000u), a1);
            a2 = fmaf(w[j], __uint_as_float(v[j].y << 16), a2);
            a3 = fmaf(w[j], __uint_as_float(v[j].y & 0xffff0000u), a3);
        }
    }
    ushort4 r;
    r.x = f2bf(a0); r.y = f2bf(a1); r.z = f2bf(a2); r.w = f2bf(a3);
    *(ushort4*)(agg16 + (size_t)n * ROW + loff) = r;
}

// ---------------------------------------------------------------- fused layer: m = relu(agg@Wrel + out@Wroot + brel); h' = GRU(m, h=out)
__global__ __launch_bounds__(256) void k_layer(int l, const unsigned short* agg16, unsigned short* out16,
                                               const unsigned short* prep, const float* brel,
                                               const float* bih, const float* bhh,
                                               float* feats, int last) {
    int f = blockIdx.y, n0 = blockIdx.x * 64;
    __shared__ unsigned short A1[64 * 72];   // agg tile (pad 64->72)
    __shared__ unsigned short A2[64 * 72];   // out (=h) tile
    __shared__ unsigned short Mt[64 * 72];   // m tile
    int tid = threadIdx.x;
    for (int t = tid; t < 512; t += 256) {   // 64 rows x 8 segs x 8 elems
        int row = t >> 3, seg = t & 7;
        int gn = n0 + row; if (gn >= NN) gn = NN - 1;
        *(uint4*)(A1 + row * 72 + seg * 8) = *(const uint4*)(agg16 + (size_t)gn * ROW + f * DD + seg * 8);
        *(uint4*)(A2 + row * 72 + seg * 8) = *(const uint4*)(out16 + (size_t)gn * ROW + f * DD + seg * 8);
    }
    __syncthreads();
    int w = tid >> 6, lane = tid & 63, mrow = lane & 15, q = lane >> 4;
    const unsigned short* wrel  = prep + f * PF_STRIDE + OFF_WREL  + l * 4096;
    const unsigned short* wroot = prep + f * PF_STRIDE + OFF_WROOT + l * 4096;

    // phase 1: m
#pragma unroll
    for (int nt = 0; nt < 4; nt++) {
        f32x4_t acc = {0.f, 0.f, 0.f, 0.f};
#pragma unroll
        for (int kb = 0; kb < 2; kb++) {
            bf16x8_t a1 = *(const bf16x8_t*)(A1 + (w * 16 + mrow) * 72 + kb * 32 + q * 8);
            bf16x8_t b1 = *(const bf16x8_t*)(wrel + ((nt * 2 + kb) * 64 + lane) * 8);
            acc = __builtin_amdgcn_mfma_f32_16x16x32_bf16(a1, b1, acc, 0, 0, 0);
            bf16x8_t a2 = *(const bf16x8_t*)(A2 + (w * 16 + mrow) * 72 + kb * 32 + q * 8);
            bf16x8_t b2 = *(const bf16x8_t*)(wroot + ((nt * 2 + kb) * 64 + lane) * 8);
            acc = __builtin_amdgcn_mfma_f32_16x16x32_bf16(a2, b2, acc, 0, 0, 0);
        }
        int col = nt * 16 + mrow;
        float bias = brel[(f * 3 + l) * DD + col];
#pragma unroll
        for (int r = 0; r < 4; r++) {
            float mv = acc[r] + bias;
            mv = mv > 0.f ? mv : 0.f;
            Mt[(w * 16 + q * 4 + r) * 72 + col] = f2bf(mv);
        }
    }
    __syncthreads();

    // phase 2: per col-tile nt, compute r/z/n gates (cols nt*16, +64, +128) for gi and gh together
    const unsigned short* wih = prep + f * PF_STRIDE + OFF_WIH;
    const unsigned short* whh = prep + f * PF_STRIDE + OFF_WHH;
#pragma unroll
    for (int nt = 0; nt < 4; nt++) {
        f32x4_t ir = {0.f,0.f,0.f,0.f}, iz = {0.f,0.f,0.f,0.f}, in_ = {0.f,0.f,0.f,0.f};
        f32x4_t hr = {0.f,0.f,0.f,0.f}, hz = {0.f,0.f,0.f,0.f}, hn  = {0.f,0.f,0.f,0.f};
#pragma unroll
        for (int kb = 0; kb < 2; kb++) {
            bf16x8_t am = *(const bf16x8_t*)(Mt + (w * 16 + mrow) * 72 + kb * 32 + q * 8);
            bf16x8_t ah = *(const bf16x8_t*)(A2 + (w * 16 + mrow) * 72 + kb * 32 + q * 8);
            bf16x8_t br = *(const bf16x8_t*)(wih + (((nt)     * 2 + kb) * 64 + lane) * 8);
            bf16x8_t bz = *(const bf16x8_t*)(wih + (((nt + 4) * 2 + kb) * 64 + lane) * 8);
            bf16x8_t bn = *(const bf16x8_t*)(wih + (((nt + 8) * 2 + kb) * 64 + lane) * 8);
            ir = __builtin_amdgcn_mfma_f32_16x16x32_bf16(am, br, ir, 0, 0, 0);
            iz = __builtin_amdgcn_mfma_f32_16x16x32_bf16(am, bz, iz, 0, 0, 0);
            in_ = __builtin_amdgcn_mfma_f32_16x16x32_bf16(am, bn, in_, 0, 0, 0);
            bf16x8_t cr = *(const bf16x8_t*)(whh + (((nt)     * 2 + kb) * 64 + lane) * 8);
            bf16x8_t cz = *(const bf16x8_t*)(whh + (((nt + 4) * 2 + kb) * 64 + lane) * 8);
            bf16x8_t cn = *(const bf16x8_t*)(whh + (((nt + 8) * 2 + kb) * 64 + lane) * 8);
            hr = __builtin_amdgcn_mfma_f32_16x16x32_bf16(ah, cr, hr, 0, 0, 0);
            hz = __builtin_amdgcn_mfma_f32_16x16x32_bf16(ah, cz, hz, 0, 0, 0);
            hn = __builtin_amdgcn_mfma_f32_16x16x32_bf16(ah, cn, hn, 0, 0, 0);
        }
        int col = nt * 16 + mrow;
        float bi_r = bih[f * 192 + col],        bh_r = bhh[f * 192 + col];
        float bi_z = bih[f * 192 + 64 + col],   bh_z = bhh[f * 192 + 64 + col];
        float bi_n = bih[f * 192 + 128 + col],  bh_n = bhh[f * 192 + 128 + col];
#pragma unroll
        for (int r = 0; r < 4; r++) {
            float rg = sigm(ir[r] + bi_r + hr[r] + bh_r);
            float z  = sigm(iz[r] + bi_z + hz[r] + bh_z);
            float nn = tanh_f(in_[r] + bi_n + rg * (hn[r] + bh_n));
            float h  = b2f(A2[(w * 16 + q * 4 + r) * 72 + col]);
            float hp = (1.f - z) * nn + z * h;
            int node = n0 + w * 16 + q * 4 + r;
            if (node < NN) {
                out16[(size_t)node * ROW + f * DD + col] = f2bf(hp);
                if (last) feats[((size_t)f * NN + node) * DD + col] = hp;
            }
        }
    }
}

// ---------------------------------------------------------------- pool (batch is sorted -> segmented reduce, few atomics)
__global__ __launch_bounds__(256) void k_pool(const float* feats, const int* batch, float* outs) {
    int f = blockIdx.y, w = threadIdx.x >> 6, lane = threadIdx.x & 63;
    int nbase = blockIdx.x * 256 + w * 64;
    if (nbase >= NN) return;
    int g_cur = batch[nbase];
    float acc = 0.f;
    for (int i = 0; i < 64; i++) {
        int n = nbase + i;
        if (n >= NN) break;
        int g = batch[n];
        float v = feats[((size_t)f * NN + n) * DD + lane];
        if (g != g_cur) {
            atomicAdd(&outs[(f * GG + g_cur) * DD + lane], acc);
            acc = v; g_cur = g;
        } else acc += v;
    }
    atomicAdd(&outs[(f * GG + g_cur) * DD + lane], acc);
}
__global__ __launch_bounds__(256) void k_norm(float* outs, const float* counts) {
    int i = blockIdx.x * 256 + threadIdx.x;
    if (i < NFAC * GG * DD) {
        int g = (i >> 6) & (GG - 1);
        outs[i] /= fmaxf(counts[g], 1.f);
    }
}

// ---------------------------------------------------------------- launch
extern "C" void kernel_launch(void* const* d_in, const int* in_sizes, int n_in,
                              void* d_out, int out_size, void* d_ws, size_t ws_size,
                              hipStream_t stream) {
    const float* x    = (const float*)d_in[0];
    const int*   ei   = (const int*)d_in[1];
    const float* att  = (const float*)d_in[2];
    const int*   batch= (const int*)d_in[3];
    const float* linW = (const float*)d_in[4];
    const float* linb = (const float*)d_in[5];
    const float* wrel = (const float*)d_in[6];
    const float* brel = (const float*)d_in[7];
    const float* wroot= (const float*)d_in[8];
    const float* wih  = (const float*)d_in[9];
    const float* whh  = (const float*)d_in[10];
    const float* bih  = (const float*)d_in[11];
    const float* bhh  = (const float*)d_in[12];

    float* outs  = (float*)d_out;                  // [4,128,64]
    float* feats = (float*)d_out + NFAC * GG * DD; // [4,N,64]

    char* p = (char*)d_ws;
    unsigned short* out16 = (unsigned short*)p; p += (size_t)NN * ROW * 2;
    unsigned short* agg16 = (unsigned short*)p; p += (size_t)NN * ROW * 2;
    unsigned short* x16   = (unsigned short*)p; p += (size_t)NN * FDIM * 2;
    unsigned short* prep  = (unsigned short*)p; p += (size_t)PREP_TOTAL * 2;
    float* csr_att        = (float*)p;          p += (size_t)EE * 16;
    int* csr_src          = (int*)p;            p += (size_t)EE * 4;
    int* deg              = (int*)p;            p += (size_t)NN * 4;
    int* cursor           = (int*)p;            p += (size_t)NN * 4;
    int* row_pos          = (int*)p;            p += (size_t)NN * 4;
    int* row_ptr          = (int*)p;            p += (size_t)(NN + 1) * 4;
    int* boff             = (int*)p;            p += 512 * 4;
    float* counts         = (float*)p;          p += 512;

    k_init  <<<dim3(391),  dim3(256), 0, stream>>>(deg, cursor, outs);
    k_prep  <<<dim3(4096), dim3(256), 0, stream>>>(x, linW, wrel, wroot, wih, whh, x16, prep);
    k_count <<<dim3(1),    dim3(256), 0, stream>>>(batch, counts);
    k_deg   <<<dim3(6250), dim3(256), 0, stream>>>(ei, deg);
    k_scan1 <<<dim3(391),  dim3(256), 0, stream>>>(deg, row_pos, boff);
    k_scan2 <<<dim3(1),    dim3(512), 0, stream>>>(boff);
    k_rowptr<<<dim3(391),  dim3(256), 0, stream>>>(row_pos, boff, row_ptr);
    k_fill  <<<dim3(6250), dim3(256), 0, stream>>>(ei, att, row_ptr, cursor, csr_src, csr_att);
    k_lin   <<<dim3(1563, 4), dim3(256), 0, stream>>>(x16, prep, linb, out16);
    for (int l = 0; l < NLAY; l++) {
        k_gather<<<dim3(25000),   dim3(256), 0, stream>>>(row_ptr, csr_src, csr_att, out16, agg16);
        k_layer <<<dim3(1563, 4), dim3(256), 0, stream>>>(l, agg16, out16, prep, brel, bih, bhh,
                                                          feats, (l == NLAY - 1) ? 1 : 0);
    }
    k_pool <<<dim3(391, 4), dim3(256), 0, stream>>>(feats, batch, outs);
    k_norm <<<dim3(128),    dim3(256), 0, stream>>>(outs, counts);
}